// Round 3
// baseline (82.559 us; speedup 1.0000x reference)
//
#include <hip/hip_runtime.h>

#define BATCH 262144
#define BLOCK 256

struct c2f { float re, im; };

__device__ __forceinline__ c2f cmul(c2f a, c2f b){
    return { a.re*b.re - a.im*b.im, a.re*b.im + a.im*b.re };
}
__device__ __forceinline__ c2f cmulc(c2f a, c2f b){  // a * conj(b)
    return { a.re*b.re + a.im*b.im, a.im*b.re - a.re*b.im };
}
// SU(2) matrices stored as (alpha, beta): M = [[a, b], [-conj(b), conj(a)]]
__device__ __forceinline__ void su2mul(c2f a1, c2f b1, c2f a2, c2f b2, c2f& ao, c2f& bo){
    c2f t1 = cmul(a1, a2), t2 = cmulc(b1, b2);
    ao = { t1.re - t2.re, t1.im - t2.im };
    c2f t3 = cmul(a1, b2), t4 = cmulc(b1, a2);
    bo = { t3.re + t4.re, t3.im + t4.im };
}
// CZ diagonal sign: -1 iff parity of adjacent-pair AND products is odd.
// qubit 0 = MSB (bit 3). Pairs (0,1),(1,2),(2,3),(0,3). Negative states: {3,6,9,12}.
__device__ __forceinline__ int czneg(int s){
    int b0 = (s >> 3) & 1, b1 = (s >> 2) & 1, b2 = (s >> 1) & 1, b3 = s & 1;
    return (b0 & b1) ^ (b1 & b2) ^ (b2 & b3) ^ (b0 & b3);
}

__global__ __launch_bounds__(BLOCK) void vqc_kernel(
    const float* __restrict__ x,      // (BATCH,4) f32
    const float* __restrict__ theta,  // 48 f32
    const float* __restrict__ lmbd,   // 12 f32
    float* __restrict__ out)          // (BATCH,4) f32
{
    const int tid = threadIdx.x;
    // Issue the per-thread x load FIRST — its ~400-900 cy HBM latency hides
    // under the batch-independent shared-memory precompute + barriers below.
    const int b = blockIdx.x * BLOCK + tid;
    const float4 xr = ((const float4*)x)[b];

    // --- per-block precompute of batch-independent SU(2) factors ---
    __shared__ float2 sU[4][4][2];   // [param layer 0..3][qubit][alpha,beta]
    __shared__ float2 sA[3][4][2];   // A^(0)=U1*W, A^(1)=U2*W, A^(2)=W  (W=U3)
    __shared__ float2 sPsi0[16];     // CZ * (tensor U^(0)) |0>
    __shared__ float  sL[12];        // lmbd

    if (tid < 16) {
        int l = tid >> 2, q = tid & 3;
        float t0 = 0.5f * theta[(l * 4 + q) * 3 + 0];
        float t1 = 0.5f * theta[(l * 4 + q) * 3 + 1];
        float t2 = 0.5f * theta[(l * 4 + q) * 3 + 2];
        float c0, s0, c1, s1, c2v, s2v;
        __sincosf(t0, &s0, &c0);
        __sincosf(t1, &s1, &c1);
        __sincosf(t2, &s2v, &c2v);
        // RY(t1)*RX(t0): alpha = c1 c0 + i s1 s0 ; beta = -s1 c0 - i c1 s0
        c2f aP = { c1 * c0, s1 * s0 };
        c2f bP = { -s1 * c0, -c1 * s0 };
        // RZ(t2)*P: multiply (alpha,beta) by e^{-i t2/2}
        c2f ph = { c2v, -s2v };
        c2f aU = cmul(ph, aP);
        c2f bU = cmul(ph, bP);
        sU[l][q][0] = make_float2(aU.re, aU.im);
        sU[l][q][1] = make_float2(bU.re, bU.im);
    }
    if (tid < 12) sL[tid] = lmbd[tid];
    __syncthreads();

    if (tid < 12) {
        int k = tid >> 2, q = tid & 3;
        c2f aW = { sU[3][q][0].x, sU[3][q][0].y };
        c2f bW = { sU[3][q][1].x, sU[3][q][1].y };
        c2f aA = aW, bA = bW;
        if (k < 2) {
            c2f aN = { sU[k + 1][q][0].x, sU[k + 1][q][0].y };
            c2f bN = { sU[k + 1][q][1].x, sU[k + 1][q][1].y };
            su2mul(aN, bN, aW, bW, aA, bA);   // U^(k+1) * W
        }
        sA[k][q][0] = make_float2(aA.re, aA.im);
        sA[k][q][1] = make_float2(bA.re, bA.im);
    }
    if (tid >= 16 && tid < 32) {
        int s = tid - 16;
        c2f v = { 1.f, 0.f };
        #pragma unroll
        for (int q = 0; q < 4; ++q) {
            int bit = (s >> (3 - q)) & 1;
            // column 0 of U: bit0 -> alpha ; bit1 -> -conj(beta)
            c2f a = { sU[0][q][0].x, sU[0][q][0].y };
            c2f b2 = { sU[0][q][1].x, sU[0][q][1].y };
            c2f e = bit ? c2f{ -b2.re, b2.im } : a;
            v = cmul(v, e);
        }
        if (czneg(s)) { v.re = -v.re; v.im = -v.im; }
        sPsi0[s] = make_float2(v.re, v.im);
    }
    __syncthreads();

    // --- per-thread statevector simulation: 32 NAMED scalar registers,
    //     every index literal (macro-expanded; nothing for the compiler to
    //     fail to unroll / promote) ---
    // NOTE: macro parameter must NOT be named 'i' — the imaginary-part
    // suffix letter 'i' would get token-pasted too (p##i##i -> p00).

#define DECLP(n) float p##n##r = sPsi0[n].x, p##n##i = sPsi0[n].y;
    DECLP(0)  DECLP(1)  DECLP(2)  DECLP(3)
    DECLP(4)  DECLP(5)  DECLP(6)  DECLP(7)
    DECLP(8)  DECLP(9)  DECLP(10) DECLP(11)
    DECLP(12) DECLP(13) DECLP(14) DECLP(15)
#undef DECLP

    // butterfly on pair (i0,i1) with gate (aM, bM); matches reference exactly
#define BF(i0,i1) { \
    const float q0r=p##i0##r, q0i=p##i0##i, q1r=p##i1##r, q1i=p##i1##i; \
    p##i0##r =  aMr*q0r - aMi*q0i + bMr*q1r - bMi*q1i; \
    p##i0##i =  aMr*q0i + aMi*q0r + bMr*q1i + bMi*q1r; \
    p##i1##r = -bMr*q0r - bMi*q0i + aMr*q1r + aMi*q1i; \
    p##i1##i = -bMr*q0i + bMi*q0r + aMr*q1i - aMi*q1r; \
}

    // Fused gate M = A^(kk) * RZ(z)*RY(a)*RX(a)  (all indices literal)
#define GATE(kk,qq,zq,...) { \
    const float c_ = ch##qq, s_ = sh##qq; \
    const float cz_ = ch##zq, sz_ = sh##zq; \
    const float cc_ = c_*c_, ss_ = s_*s_, cs_ = c_*s_; \
    const float aVr = cc_*cz_ + ss_*sz_, aVi = ss_*cz_ - cc_*sz_; \
    const float bVr = -cs_*(cz_+sz_),  bVi = -cs_*(cz_-sz_); \
    const float2 fa = sA[kk][qq][0], fb = sA[kk][qq][1]; \
    const float aMr = fa.x*aVr - fa.y*aVi - (fb.x*bVr + fb.y*bVi); \
    const float aMi = fa.x*aVi + fa.y*aVr - (fb.y*bVr - fb.x*bVi); \
    const float bMr = fa.x*bVr - fa.y*bVi + (fb.x*aVr + fb.y*aVi); \
    const float bMi = fa.x*bVi + fa.y*bVr + (fb.y*aVr - fb.x*aVi); \
    __VA_ARGS__ \
}

    // CZ sign flips: negative diagonal on states {3,6,9,12}
#define CZFLIP \
    p3r  = -p3r;  p3i  = -p3i;  p6r  = -p6r;  p6i  = -p6i; \
    p9r  = -p9r;  p9i  = -p9i;  p12r = -p12r; p12i = -p12i;

#define LAYER(kk, DO_CZ) { \
    const float h0 = 0.5f * sL[kk*4+0] * xr.x; \
    const float h1 = 0.5f * sL[kk*4+1] * xr.y; \
    const float h2 = 0.5f * sL[kk*4+2] * xr.z; \
    const float h3 = 0.5f * sL[kk*4+3] * xr.w; \
    float ch0, sh0, ch1, sh1, ch2, sh2, ch3, sh3; \
    __sincosf(h0, &sh0, &ch0); \
    __sincosf(h1, &sh1, &ch1); \
    __sincosf(h2, &sh2, &ch2); \
    __sincosf(h3, &sh3, &ch3); \
    GATE(kk,0,0, BF(0,8)  BF(1,9)  BF(2,10) BF(3,11) BF(4,12) BF(5,13) BF(6,14)  BF(7,15))  \
    GATE(kk,1,0, BF(0,4)  BF(1,5)  BF(2,6)  BF(3,7)  BF(8,12) BF(9,13) BF(10,14) BF(11,15)) \
    GATE(kk,2,1, BF(0,2)  BF(1,3)  BF(4,6)  BF(5,7)  BF(8,10) BF(9,11) BF(12,14) BF(13,15)) \
    GATE(kk,3,1, BF(0,1)  BF(2,3)  BF(4,5)  BF(6,7)  BF(8,9)  BF(10,11) BF(12,13) BF(14,15))\
    if (DO_CZ) { CZFLIP } \
}

    LAYER(0, 1)
    LAYER(1, 1)
    LAYER(2, 0)

#undef LAYER
#undef GATE
#undef BF
#undef CZFLIP

    // probs and Z expectations (qubit j reads bit (3-j))
#define PROB(n) const float m##n = p##n##r*p##n##r + p##n##i*p##n##i;
    PROB(0)  PROB(1)  PROB(2)  PROB(3)
    PROB(4)  PROB(5)  PROB(6)  PROB(7)
    PROB(8)  PROB(9)  PROB(10) PROB(11)
    PROB(12) PROB(13) PROB(14) PROB(15)
#undef PROB

    const float o0 = ((m0+m1)+(m2+m3)+(m4+m5)+(m6+m7))
                   - ((m8+m9)+(m10+m11)+(m12+m13)+(m14+m15));
    const float o1 = ((m0+m1)+(m2+m3)+(m8+m9)+(m10+m11))
                   - ((m4+m5)+(m6+m7)+(m12+m13)+(m14+m15));
    const float o2 = ((m0+m1)+(m4+m5)+(m8+m9)+(m12+m13))
                   - ((m2+m3)+(m6+m7)+(m10+m11)+(m14+m15));
    const float o3 = ((m0+m2)+(m4+m6)+(m8+m10)+(m12+m14))
                   - ((m1+m3)+(m5+m7)+(m9+m11)+(m13+m15));

    ((float4*)out)[b] = make_float4(o0, o1, o2, o3);
}

extern "C" void kernel_launch(void* const* d_in, const int* in_sizes, int n_in,
                              void* d_out, int out_size, void* d_ws, size_t ws_size,
                              hipStream_t stream) {
    const float* x     = (const float*)d_in[0];
    const float* theta = (const float*)d_in[1];
    const float* lmbd  = (const float*)d_in[2];
    float* out = (float*)d_out;
    vqc_kernel<<<dim3(BATCH / BLOCK), dim3(BLOCK), 0, stream>>>(x, theta, lmbd, out);
}

// Round 4
// 72.627 us; speedup vs baseline: 1.1368x; 1.1368x over previous
//
#include <hip/hip_runtime.h>

#define BATCH 262144
#define BLOCK 256

struct c2f { float re, im; };

__device__ __forceinline__ c2f cmul(c2f a, c2f b){
    return { a.re*b.re - a.im*b.im, a.re*b.im + a.im*b.re };
}
__device__ __forceinline__ c2f cmulc(c2f a, c2f b){  // a * conj(b)
    return { a.re*b.re + a.im*b.im, a.im*b.re - a.re*b.im };
}
// SU(2) matrices stored as (alpha, beta): M = [[a, b], [-conj(b), conj(a)]]
__device__ __forceinline__ void su2mul(c2f a1, c2f b1, c2f a2, c2f b2, c2f& ao, c2f& bo){
    c2f t1 = cmul(a1, a2), t2 = cmulc(b1, b2);
    ao = { t1.re - t2.re, t1.im - t2.im };
    c2f t3 = cmul(a1, b2), t4 = cmulc(b1, a2);
    bo = { t3.re + t4.re, t3.im + t4.im };
}
// CZ diagonal sign: -1 iff parity of adjacent-pair AND products is odd.
// qubit 0 = MSB (bit 3). Pairs (0,1),(1,2),(2,3),(0,3). Negative states: {3,6,9,12}.
__device__ __forceinline__ int czneg(int s){
    int b0 = (s >> 3) & 1, b1 = (s >> 2) & 1, b2 = (s >> 1) & 1, b3 = s & 1;
    return (b0 & b1) ^ (b1 & b2) ^ (b2 & b3) ^ (b0 & b3);
}

__global__ __launch_bounds__(BLOCK) void vqc_kernel(
    const float* __restrict__ x,      // (BATCH,4) f32
    const float* __restrict__ theta,  // 48 f32
    const float* __restrict__ lmbd,   // 12 f32
    float* __restrict__ out)          // (BATCH,4) f32
{
    const int tid = threadIdx.x;
    // Issue the per-thread x load FIRST — HBM latency hides under the
    // batch-independent shared-memory precompute + barriers below.
    const int b = blockIdx.x * BLOCK + tid;
    const float4 xr = ((const float4*)x)[b];

    // --- per-block precompute of batch-independent SU(2) factors ---
    __shared__ float2 sU[4][4][2];   // [param layer 0..3][qubit][alpha,beta]
    __shared__ float2 sA[3][4][2];   // A^(0)=U1*W, A^(1)=U2*W, A^(2)=W  (W=U3)
    __shared__ float2 sPsi0[16];     // CZ * (tensor U^(0)) |0>
    __shared__ float  sL[12];        // lmbd

    if (tid < 16) {
        int l = tid >> 2, q = tid & 3;
        float t0 = 0.5f * theta[(l * 4 + q) * 3 + 0];
        float t1 = 0.5f * theta[(l * 4 + q) * 3 + 1];
        float t2 = 0.5f * theta[(l * 4 + q) * 3 + 2];
        float c0, s0, c1, s1, c2v, s2v;
        __sincosf(t0, &s0, &c0);
        __sincosf(t1, &s1, &c1);
        __sincosf(t2, &s2v, &c2v);
        // RY(t1)*RX(t0): alpha = c1 c0 + i s1 s0 ; beta = -s1 c0 - i c1 s0
        c2f aP = { c1 * c0, s1 * s0 };
        c2f bP = { -s1 * c0, -c1 * s0 };
        // RZ(t2)*P: multiply (alpha,beta) by e^{-i t2/2}
        c2f ph = { c2v, -s2v };
        c2f aU = cmul(ph, aP);
        c2f bU = cmul(ph, bP);
        sU[l][q][0] = make_float2(aU.re, aU.im);
        sU[l][q][1] = make_float2(bU.re, bU.im);
    }
    if (tid < 12) sL[tid] = lmbd[tid];
    __syncthreads();

    if (tid < 12) {
        int k = tid >> 2, q = tid & 3;
        c2f aW = { sU[3][q][0].x, sU[3][q][0].y };
        c2f bW = { sU[3][q][1].x, sU[3][q][1].y };
        c2f aA = aW, bA = bW;
        if (k < 2) {
            c2f aN = { sU[k + 1][q][0].x, sU[k + 1][q][0].y };
            c2f bN = { sU[k + 1][q][1].x, sU[k + 1][q][1].y };
            su2mul(aN, bN, aW, bW, aA, bA);   // U^(k+1) * W
        }
        sA[k][q][0] = make_float2(aA.re, aA.im);
        sA[k][q][1] = make_float2(bA.re, bA.im);
    }
    if (tid >= 16 && tid < 32) {
        int s = tid - 16;
        c2f v = { 1.f, 0.f };
        #pragma unroll
        for (int q = 0; q < 4; ++q) {
            int bit = (s >> (3 - q)) & 1;
            // column 0 of U: bit0 -> alpha ; bit1 -> -conj(beta)
            c2f a = { sU[0][q][0].x, sU[0][q][0].y };
            c2f b2 = { sU[0][q][1].x, sU[0][q][1].y };
            c2f e = bit ? c2f{ -b2.re, b2.im } : a;
            v = cmul(v, e);
        }
        if (czneg(s)) { v.re = -v.re; v.im = -v.im; }
        sPsi0[s] = make_float2(v.re, v.im);
    }
    __syncthreads();

    // --- per-thread statevector simulation ---
    // State held as 16 float2 (re,im). The butterfly is written as paired
    // .x/.y FMA chains with identical structure — the exact SLP pattern for
    // v_pk_fma_f32 (packed 2xf32 FMA) on gfx950. Scalar fallback is
    // instruction-count-identical to the previous version (rot() signs fold
    // into fma neg modifiers).

#define DECLP(n) float2 p##n = sPsi0[n];
    DECLP(0)  DECLP(1)  DECLP(2)  DECLP(3)
    DECLP(4)  DECLP(5)  DECLP(6)  DECLP(7)
    DECLP(8)  DECLP(9)  DECLP(10) DECLP(11)
    DECLP(12) DECLP(13) DECLP(14) DECLP(15)
#undef DECLP

    // new0 = aM*q0 + bM*q1 ;  new1 = -conj(bM)*q0 + conj(aM)*q1
    // complex mul via packed form:  aM*q = aMr*q + aMi*rot(q), rot(q)=(-q.y,q.x)
#define BF(n0,n1) { \
    const float2 q0 = p##n0, q1 = p##n1; \
    const float r0x = -q0.y, r0y = q0.x; \
    const float r1x = -q1.y, r1y = q1.x; \
    float2 t0, t1; \
    t0.x = aMr*q0.x;              t0.y = aMr*q0.y; \
    t0.x = fmaf(aMi, r0x, t0.x);  t0.y = fmaf(aMi, r0y, t0.y); \
    t0.x = fmaf(bMr, q1.x, t0.x); t0.y = fmaf(bMr, q1.y, t0.y); \
    t0.x = fmaf(bMi, r1x, t0.x);  t0.y = fmaf(bMi, r1y, t0.y); \
    t1.x = aMr*q1.x;              t1.y = aMr*q1.y; \
    t1.x = fmaf(aMi, -r1x, t1.x); t1.y = fmaf(aMi, -r1y, t1.y); \
    t1.x = fmaf(bMr, -q0.x, t1.x);t1.y = fmaf(bMr, -q0.y, t1.y); \
    t1.x = fmaf(bMi, r0x, t1.x);  t1.y = fmaf(bMi, r0y, t1.y); \
    p##n0 = t0; p##n1 = t1; \
}

    // Fused gate M = A^(kk) * RZ(z)*RY(a)*RX(a)  (all indices literal)
#define GATE(kk,qq,zq,...) { \
    const float c_ = ch##qq, s_ = sh##qq; \
    const float cz_ = ch##zq, sz_ = sh##zq; \
    const float cc_ = c_*c_, ss_ = s_*s_, cs_ = c_*s_; \
    const float aVr = cc_*cz_ + ss_*sz_, aVi = ss_*cz_ - cc_*sz_; \
    const float bVr = -cs_*(cz_+sz_),  bVi = -cs_*(cz_-sz_); \
    const float2 fa = sA[kk][qq][0], fb = sA[kk][qq][1]; \
    const float aMr = fa.x*aVr - fa.y*aVi - (fb.x*bVr + fb.y*bVi); \
    const float aMi = fa.x*aVi + fa.y*aVr - (fb.y*bVr - fb.x*bVi); \
    const float bMr = fa.x*bVr - fa.y*bVi + (fb.x*aVr + fb.y*aVi); \
    const float bMi = fa.x*bVi + fa.y*bVr + (fb.y*aVr - fb.x*aVi); \
    __VA_ARGS__ \
}

    // CZ sign flips: negative diagonal on states {3,6,9,12}
#define CZFLIP \
    p3.x  = -p3.x;  p3.y  = -p3.y;  p6.x  = -p6.x;  p6.y  = -p6.y; \
    p9.x  = -p9.x;  p9.y  = -p9.y;  p12.x = -p12.x; p12.y = -p12.y;

#define LAYER(kk, DO_CZ) { \
    const float h0 = 0.5f * sL[kk*4+0] * xr.x; \
    const float h1 = 0.5f * sL[kk*4+1] * xr.y; \
    const float h2 = 0.5f * sL[kk*4+2] * xr.z; \
    const float h3 = 0.5f * sL[kk*4+3] * xr.w; \
    float ch0, sh0, ch1, sh1, ch2, sh2, ch3, sh3; \
    __sincosf(h0, &sh0, &ch0); \
    __sincosf(h1, &sh1, &ch1); \
    __sincosf(h2, &sh2, &ch2); \
    __sincosf(h3, &sh3, &ch3); \
    GATE(kk,0,0, BF(0,8)  BF(1,9)  BF(2,10) BF(3,11) BF(4,12) BF(5,13) BF(6,14)  BF(7,15))  \
    GATE(kk,1,0, BF(0,4)  BF(1,5)  BF(2,6)  BF(3,7)  BF(8,12) BF(9,13) BF(10,14) BF(11,15)) \
    GATE(kk,2,1, BF(0,2)  BF(1,3)  BF(4,6)  BF(5,7)  BF(8,10) BF(9,11) BF(12,14) BF(13,15)) \
    GATE(kk,3,1, BF(0,1)  BF(2,3)  BF(4,5)  BF(6,7)  BF(8,9)  BF(10,11) BF(12,13) BF(14,15))\
    if (DO_CZ) { CZFLIP } \
}

    LAYER(0, 1)
    LAYER(1, 1)
    LAYER(2, 0)

#undef LAYER
#undef GATE
#undef BF
#undef CZFLIP

    // probs and Z expectations (qubit j reads bit (3-j))
#define PROB(n) const float m##n = p##n.x*p##n.x + p##n.y*p##n.y;
    PROB(0)  PROB(1)  PROB(2)  PROB(3)
    PROB(4)  PROB(5)  PROB(6)  PROB(7)
    PROB(8)  PROB(9)  PROB(10) PROB(11)
    PROB(12) PROB(13) PROB(14) PROB(15)
#undef PROB

    const float o0 = ((m0+m1)+(m2+m3)+(m4+m5)+(m6+m7))
                   - ((m8+m9)+(m10+m11)+(m12+m13)+(m14+m15));
    const float o1 = ((m0+m1)+(m2+m3)+(m8+m9)+(m10+m11))
                   - ((m4+m5)+(m6+m7)+(m12+m13)+(m14+m15));
    const float o2 = ((m0+m1)+(m4+m5)+(m8+m9)+(m12+m13))
                   - ((m2+m3)+(m6+m7)+(m10+m11)+(m14+m15));
    const float o3 = ((m0+m2)+(m4+m6)+(m8+m10)+(m12+m14))
                   - ((m1+m3)+(m5+m7)+(m9+m11)+(m13+m15));

    ((float4*)out)[b] = make_float4(o0, o1, o2, o3);
}

extern "C" void kernel_launch(void* const* d_in, const int* in_sizes, int n_in,
                              void* d_out, int out_size, void* d_ws, size_t ws_size,
                              hipStream_t stream) {
    const float* x     = (const float*)d_in[0];
    const float* theta = (const float*)d_in[1];
    const float* lmbd  = (const float*)d_in[2];
    float* out = (float*)d_out;
    vqc_kernel<<<dim3(BATCH / BLOCK), dim3(BLOCK), 0, stream>>>(x, theta, lmbd, out);
}

// Round 5
// 71.896 us; speedup vs baseline: 1.1483x; 1.0102x over previous
//
#include <hip/hip_runtime.h>

#define BATCH 262144
#define BLOCK 256

typedef float v2 __attribute__((ext_vector_type(2)));

struct c2f { float re, im; };

__device__ __forceinline__ c2f cmul(c2f a, c2f b){
    return { a.re*b.re - a.im*b.im, a.re*b.im + a.im*b.re };
}
__device__ __forceinline__ c2f cmulc(c2f a, c2f b){  // a * conj(b)
    return { a.re*b.re + a.im*b.im, a.im*b.re - a.re*b.im };
}
// SU(2) matrices stored as (alpha, beta): M = [[a, b], [-conj(b), conj(a)]]
__device__ __forceinline__ void su2mul(c2f a1, c2f b1, c2f a2, c2f b2, c2f& ao, c2f& bo){
    c2f t1 = cmul(a1, a2), t2 = cmulc(b1, b2);
    ao = { t1.re - t2.re, t1.im - t2.im };
    c2f t3 = cmul(a1, b2), t4 = cmulc(b1, a2);
    bo = { t3.re + t4.re, t3.im + t4.im };
}
// CZ diagonal sign: qubit 0 = MSB (bit 3). Pairs (0,1),(1,2),(2,3),(0,3).
// Negative states: {3,6,9,12}.
__device__ __forceinline__ int czneg(int s){
    int b0 = (s >> 3) & 1, b1 = (s >> 2) & 1, b2 = (s >> 1) & 1, b3 = s & 1;
    return (b0 & b1) ^ (b1 & b2) ^ (b2 & b3) ^ (b0 & b3);
}

__device__ __forceinline__ v2 pkfma(v2 a, v2 b, v2 c){
    return __builtin_elementwise_fma(a, b, c);   // -> v_pk_fma_f32
}

__global__ __launch_bounds__(BLOCK) void vqc_kernel(
    const float* __restrict__ x,      // (BATCH,4) f32
    const float* __restrict__ theta,  // 48 f32
    const float* __restrict__ lmbd,   // 12 f32
    float* __restrict__ out)          // (BATCH,4) f32
{
    const int tid = threadIdx.x;
    // Issue the per-thread x load FIRST — HBM latency hides under the
    // batch-independent shared-memory precompute + barriers below.
    const int b = blockIdx.x * BLOCK + tid;
    const float4 xr = ((const float4*)x)[b];

    // --- per-block precompute of batch-independent SU(2) factors ---
    __shared__ float2 sU[4][4][2];   // [param layer 0..3][qubit][alpha,beta]
    __shared__ float2 sA[3][4][2];   // A^(0)=U1*W, A^(1)=U2*W, A^(2)=W  (W=U3)
    __shared__ float2 sPsi0[16];     // CZ * (tensor U^(0)) |0>
    __shared__ float  sL[12];        // lmbd

    if (tid < 16) {
        int l = tid >> 2, q = tid & 3;
        float t0 = 0.5f * theta[(l * 4 + q) * 3 + 0];
        float t1 = 0.5f * theta[(l * 4 + q) * 3 + 1];
        float t2 = 0.5f * theta[(l * 4 + q) * 3 + 2];
        float c0, s0, c1, s1, c2v, s2v;
        __sincosf(t0, &s0, &c0);
        __sincosf(t1, &s1, &c1);
        __sincosf(t2, &s2v, &c2v);
        // RY(t1)*RX(t0): alpha = c1 c0 + i s1 s0 ; beta = -s1 c0 - i c1 s0
        c2f aP = { c1 * c0, s1 * s0 };
        c2f bP = { -s1 * c0, -c1 * s0 };
        // RZ(t2)*P: multiply (alpha,beta) by e^{-i t2/2}
        c2f ph = { c2v, -s2v };
        c2f aU = cmul(ph, aP);
        c2f bU = cmul(ph, bP);
        sU[l][q][0] = make_float2(aU.re, aU.im);
        sU[l][q][1] = make_float2(bU.re, bU.im);
    }
    if (tid < 12) sL[tid] = lmbd[tid];
    __syncthreads();

    if (tid < 12) {
        int k = tid >> 2, q = tid & 3;
        c2f aW = { sU[3][q][0].x, sU[3][q][0].y };
        c2f bW = { sU[3][q][1].x, sU[3][q][1].y };
        c2f aA = aW, bA = bW;
        if (k < 2) {
            c2f aN = { sU[k + 1][q][0].x, sU[k + 1][q][0].y };
            c2f bN = { sU[k + 1][q][1].x, sU[k + 1][q][1].y };
            su2mul(aN, bN, aW, bW, aA, bA);   // U^(k+1) * W
        }
        sA[k][q][0] = make_float2(aA.re, aA.im);
        sA[k][q][1] = make_float2(bA.re, bA.im);
    }
    if (tid >= 16 && tid < 32) {
        int s = tid - 16;
        c2f v = { 1.f, 0.f };
        #pragma unroll
        for (int q = 0; q < 4; ++q) {
            int bit = (s >> (3 - q)) & 1;
            // column 0 of U: bit0 -> alpha ; bit1 -> -conj(beta)
            c2f a = { sU[0][q][0].x, sU[0][q][0].y };
            c2f b2 = { sU[0][q][1].x, sU[0][q][1].y };
            c2f e = bit ? c2f{ -b2.re, b2.im } : a;
            v = cmul(v, e);
        }
        if (czneg(s)) { v.re = -v.re; v.im = -v.im; }
        sPsi0[s] = make_float2(v.re, v.im);
    }
    __syncthreads();

    // --- per-thread statevector simulation ---
    // State = 16 named v2 (ext_vector_type(2)) registers. Every butterfly is
    // 8 explicit __builtin_elementwise_fma on v2 -> llvm.fma.v2f32 ->
    // v_pk_fma_f32. No SLP discretion left to the compiler.

#define DECLP(n) v2 p##n = { sPsi0[n].x, sPsi0[n].y };
    DECLP(0)  DECLP(1)  DECLP(2)  DECLP(3)
    DECLP(4)  DECLP(5)  DECLP(6)  DECLP(7)
    DECLP(8)  DECLP(9)  DECLP(10) DECLP(11)
    DECLP(12) DECLP(13) DECLP(14) DECLP(15)
#undef DECLP

    // new0 = aM*q0 + bM*q1 ;  new1 = -conj(bM)*q0 + conj(aM)*q1
    // complex mul packed:  aM*q = aMr*q + aMi*rot(q),  rot(q) = (-q.y, q.x)
    // conj signs appear as unary minus on v2 -> VOP3P neg_lo/neg_hi folds.
#define BF(n0,n1) { \
    const v2 q0 = p##n0, q1 = p##n1; \
    const v2 r0 = { -q0.y, q0.x }; \
    const v2 r1 = { -q1.y, q1.x }; \
    v2 t0 = bMi2 * r1; \
    t0 = pkfma(bMr2, q1, t0); \
    t0 = pkfma(aMi2, r0, t0); \
    t0 = pkfma(aMr2, q0, t0); \
    v2 t1 = bMi2 * r0; \
    t1 = pkfma(bMr2, -q0, t1); \
    t1 = pkfma(aMi2, -r1, t1); \
    t1 = pkfma(aMr2, q1, t1); \
    p##n0 = t0; p##n1 = t1; \
}

    // Fused gate M = A^(kk) * RZ(z)*RY(a)*RX(a)  (all indices literal)
#define GATE(kk,qq,zq,...) { \
    const float c_ = ch##qq, s_ = sh##qq; \
    const float cz_ = ch##zq, sz_ = sh##zq; \
    const float cc_ = c_*c_, ss_ = s_*s_, cs_ = c_*s_; \
    const float aVr = cc_*cz_ + ss_*sz_, aVi = ss_*cz_ - cc_*sz_; \
    const float bVr = -cs_*(cz_+sz_),  bVi = -cs_*(cz_-sz_); \
    const float2 fa = sA[kk][qq][0], fb = sA[kk][qq][1]; \
    const float aMr = fa.x*aVr - fa.y*aVi - (fb.x*bVr + fb.y*bVi); \
    const float aMi = fa.x*aVi + fa.y*aVr - (fb.y*bVr - fb.x*bVi); \
    const float bMr = fa.x*bVr - fa.y*bVi + (fb.x*aVr + fb.y*aVi); \
    const float bMi = fa.x*bVi + fa.y*bVr + (fb.y*aVr - fb.x*aVi); \
    const v2 aMr2 = { aMr, aMr }, aMi2 = { aMi, aMi }; \
    const v2 bMr2 = { bMr, bMr }, bMi2 = { bMi, bMi }; \
    __VA_ARGS__ \
}

    // CZ sign flips: negative diagonal on states {3,6,9,12}
#define CZFLIP \
    p3 = -p3;  p6 = -p6;  p9 = -p9;  p12 = -p12;

#define LAYER(kk, DO_CZ) { \
    const float h0 = 0.5f * sL[kk*4+0] * xr.x; \
    const float h1 = 0.5f * sL[kk*4+1] * xr.y; \
    const float h2 = 0.5f * sL[kk*4+2] * xr.z; \
    const float h3 = 0.5f * sL[kk*4+3] * xr.w; \
    float ch0, sh0, ch1, sh1, ch2, sh2, ch3, sh3; \
    __sincosf(h0, &sh0, &ch0); \
    __sincosf(h1, &sh1, &ch1); \
    __sincosf(h2, &sh2, &ch2); \
    __sincosf(h3, &sh3, &ch3); \
    GATE(kk,0,0, BF(0,8)  BF(1,9)  BF(2,10) BF(3,11) BF(4,12) BF(5,13) BF(6,14)  BF(7,15))  \
    GATE(kk,1,0, BF(0,4)  BF(1,5)  BF(2,6)  BF(3,7)  BF(8,12) BF(9,13) BF(10,14) BF(11,15)) \
    GATE(kk,2,1, BF(0,2)  BF(1,3)  BF(4,6)  BF(5,7)  BF(8,10) BF(9,11) BF(12,14) BF(13,15)) \
    GATE(kk,3,1, BF(0,1)  BF(2,3)  BF(4,5)  BF(6,7)  BF(8,9)  BF(10,11) BF(12,13) BF(14,15))\
    if (DO_CZ) { CZFLIP } \
}

    LAYER(0, 1)
    LAYER(1, 1)
    LAYER(2, 0)

#undef LAYER
#undef GATE
#undef BF
#undef CZFLIP

    // probs and Z expectations (qubit j reads bit (3-j))
#define PROB(n) const float m##n = p##n.x*p##n.x + p##n.y*p##n.y;
    PROB(0)  PROB(1)  PROB(2)  PROB(3)
    PROB(4)  PROB(5)  PROB(6)  PROB(7)
    PROB(8)  PROB(9)  PROB(10) PROB(11)
    PROB(12) PROB(13) PROB(14) PROB(15)
#undef PROB

    const float o0 = ((m0+m1)+(m2+m3)+(m4+m5)+(m6+m7))
                   - ((m8+m9)+(m10+m11)+(m12+m13)+(m14+m15));
    const float o1 = ((m0+m1)+(m2+m3)+(m8+m9)+(m10+m11))
                   - ((m4+m5)+(m6+m7)+(m12+m13)+(m14+m15));
    const float o2 = ((m0+m1)+(m4+m5)+(m8+m9)+(m12+m13))
                   - ((m2+m3)+(m6+m7)+(m10+m11)+(m14+m15));
    const float o3 = ((m0+m2)+(m4+m6)+(m8+m10)+(m12+m14))
                   - ((m1+m3)+(m5+m7)+(m9+m11)+(m13+m15));

    ((float4*)out)[b] = make_float4(o0, o1, o2, o3);
}

extern "C" void kernel_launch(void* const* d_in, const int* in_sizes, int n_in,
                              void* d_out, int out_size, void* d_ws, size_t ws_size,
                              hipStream_t stream) {
    const float* x     = (const float*)d_in[0];
    const float* theta = (const float*)d_in[1];
    const float* lmbd  = (const float*)d_in[2];
    float* out = (float*)d_out;
    vqc_kernel<<<dim3(BATCH / BLOCK), dim3(BLOCK), 0, stream>>>(x, theta, lmbd, out);
}